// Round 4
// baseline (536.595 us; speedup 1.0000x reference)
//
#include <hip/hip_runtime.h>

// AttDownsample: x [32,768,56,56] f32 -> y [32,768,28,28] f32
// 3-kernel split: (1) partial scores -> partials[chunk][pix][9] (no atomics),
// (2) reduce+softmax -> attn[pix][9], (3) merge.
// ws layout: partials 48*25088*9 f32 (43.35 MB) | attn 25088*9 f32 (903 KB).

constexpr int N_  = 32;
constexpr int C_  = 768;
constexpr int H_  = 56;
constexpr int W_  = 56;
constexpr int HO_ = 28;
constexpr int WO_ = 28;
constexpr int NPIX = N_ * HO_ * WO_;          // 25088

// ---- kernel 1: partial scores ----
constexpr int K1_CB     = 16;                  // channels per block
constexpr int K1_NCHUNK = C_ / K1_CB;          // 48 (exact)
constexpr int K1_TW     = 58;                  // row stride in tile
constexpr int K1_TILE   = K1_CB * 3 * K1_TW;   // 2784 floats

__global__ __launch_bounds__(256)
void scores_kernel(const float* __restrict__ x, float* __restrict__ partials) {
    __shared__ float tile_raw[4 + K1_TILE];    // +4 front pad: col -1 reads hit zero, f4 alignment kept
    __shared__ float sred[8 * WO_ * 9];        // [g][wo][k]
    float* tile = tile_raw + 4;

    const int tid   = threadIdx.x;
    const int blk   = blockIdx.x;
    const int chunk = blk / (N_ * HO_);
    const int nho   = blk % (N_ * HO_);
    const int n     = nho / HO_;
    const int ho    = nho % HO_;
    const int cbase = chunk * K1_CB;
    const int row0  = 2 * ho - 1;

    for (int i = tid; i < 4 + K1_TILE; i += 256) tile_raw[i] = 0.f;
    __syncthreads();

    const float* xb = x + (size_t)n * (C_ * H_ * W_);
    // 16 ch x 3 rows x 14 float4 = 672 vector loads
    for (int i = tid; i < 672; i += 256) {
        int c   = i / 42;
        int rem = i - c * 42;
        int r   = rem / 14;
        int kk  = rem - r * 14;
        int grow = row0 + r;
        if (grow >= 0) {
            float4 v = *(const float4*)(xb + ((size_t)(cbase + c) * H_ + grow) * W_ + 4 * kk);
            float* d = &tile[c * (3 * K1_TW) + r * K1_TW + 4 * kk];
            d[0] = v.x; d[1] = v.y; d[2] = v.z; d[3] = v.w;
        }
    }
    __syncthreads();

    const int wo = tid % WO_;
    const int g  = tid / WO_;                  // 0..9, active g<8, 2 channels each
    if (g < 8) {
        float sacc[9];
#pragma unroll
        for (int k = 0; k < 9; ++k) sacc[k] = 0.f;
#pragma unroll
        for (int cc = 0; cc < 2; ++cc) {
            const float* tp = &tile[(g * 2 + cc) * (3 * K1_TW) + 2 * wo - 1];
            float w0 = tp[0],          w1 = tp[1],            w2 = tp[2];
            float w3 = tp[K1_TW],      w4 = tp[K1_TW + 1],    w5 = tp[K1_TW + 2];
            float w6 = tp[2 * K1_TW],  w7 = tp[2 * K1_TW + 1], w8 = tp[2 * K1_TW + 2];
            float q = (w0 + w1 + w2 + w3 + w4 + w5 + w6 + w7 + w8) * (1.f / 9.f);
            sacc[0] += q * w0; sacc[1] += q * w1; sacc[2] += q * w2;
            sacc[3] += q * w3; sacc[4] += q * w4; sacc[5] += q * w5;
            sacc[6] += q * w6; sacc[7] += q * w7; sacc[8] += q * w8;
        }
#pragma unroll
        for (int k = 0; k < 9; ++k) sred[(g * WO_ + wo) * 9 + k] = sacc[k];
    }
    __syncthreads();

    if (tid < WO_ * 9) {
        int wo2 = tid / 9, k = tid - wo2 * 9;
        float t = 0.f;
#pragma unroll
        for (int g2 = 0; g2 < 8; ++g2) t += sred[(g2 * WO_ + wo2) * 9 + k];
        // pixel index within [N,Ho,Wo]: nho*WO_ + wo2; coalesced 252-float run per block
        partials[((size_t)chunk * NPIX + nho * WO_ + wo2) * 9 + k] = t * (1.f / 3.f);
    }
}

// ---- kernel 2: reduce over 48 chunks + softmax over k=9 ----
__global__ __launch_bounds__(256)
void softmax_kernel(const float* __restrict__ partials, float* __restrict__ attn) {
    int p = blockIdx.x * 256 + threadIdx.x;
    if (p >= NPIX) return;
    float s[9];
#pragma unroll
    for (int k = 0; k < 9; ++k) s[k] = 0.f;
    for (int c = 0; c < K1_NCHUNK; ++c) {
        const float* pp = partials + ((size_t)c * NPIX + p) * 9;
#pragma unroll
        for (int k = 0; k < 9; ++k) s[k] += pp[k];
    }
    float m = s[0];
#pragma unroll
    for (int k = 1; k < 9; ++k) m = fmaxf(m, s[k]);
    float d = 0.f;
#pragma unroll
    for (int k = 0; k < 9; ++k) { s[k] = __expf(s[k] - m); d += s[k]; }
    float inv = 1.f / d;
    float* ap = attn + (size_t)p * 9;
#pragma unroll
    for (int k = 0; k < 9; ++k) ap[k] = s[k] * inv;
}

// ---- kernel 3: merge. one block per (n,c) plane ----
constexpr int K3_TW = 58;                      // rows 0..57 (ghost top at 0), cols 0..55 data

__global__ __launch_bounds__(256)
void merge_kernel(const float* __restrict__ x, const float* __restrict__ attn,
                  float* __restrict__ out) {
    __shared__ float tile_raw[4 + K3_TW * K3_TW];
    float* tile = tile_raw + 4;

    const int tid = threadIdx.x;
    const int blk = blockIdx.x;
    const int n   = blk / C_;                  // consecutive blocks share n -> attn L2-hot
    const int c   = blk - n * C_;

    for (int i = tid; i < 4 + K3_TW * K3_TW; i += 256) tile_raw[i] = 0.f;
    __syncthreads();

    const float* xp = x + ((size_t)n * C_ + c) * (H_ * W_);
    // 56 rows x 14 float4; input row r -> tile row r+1 (ghost top row 0 stays zero)
    for (int i = tid; i < 784; i += 256) {
        int r  = i / 14;
        int kk = i - r * 14;
        float4 v = *(const float4*)(xp + (size_t)r * W_ + 4 * kk);
        float* d = &tile[(r + 1) * K3_TW + 4 * kk];
        d[0] = v.x; d[1] = v.y; d[2] = v.z; d[3] = v.w;
    }
    __syncthreads();

    float* op = out + ((size_t)n * C_ + c) * (HO_ * WO_);
    const float* ap = attn + (size_t)n * (HO_ * WO_) * 9;
    for (int p = tid; p < HO_ * WO_; p += 256) {
        int ho = p / WO_, wo = p - ho * WO_;
        const float* a  = &ap[(size_t)p * 9];
        const float* tp = &tile[(size_t)(2 * ho) * K3_TW + 2 * wo - 1];
        float y = a[0] * tp[0]           + a[1] * tp[1]             + a[2] * tp[2]
                + a[3] * tp[K3_TW]       + a[4] * tp[K3_TW + 1]     + a[5] * tp[K3_TW + 2]
                + a[6] * tp[2 * K3_TW]   + a[7] * tp[2 * K3_TW + 1] + a[8] * tp[2 * K3_TW + 2];
        op[p] = y;
    }
}

extern "C" void kernel_launch(void* const* d_in, const int* in_sizes, int n_in,
                              void* d_out, int out_size, void* d_ws, size_t ws_size,
                              hipStream_t stream) {
    const float* x   = (const float*)d_in[0];
    float* out       = (float*)d_out;
    float* partials  = (float*)d_ws;                                   // 48*NPIX*9 f32
    float* attn      = partials + (size_t)K1_NCHUNK * NPIX * 9;        // NPIX*9 f32

    scores_kernel<<<dim3(K1_NCHUNK * N_ * HO_), dim3(256), 0, stream>>>(x, partials);
    softmax_kernel<<<dim3((NPIX + 255) / 256), dim3(256), 0, stream>>>(partials, attn);
    merge_kernel<<<dim3(N_ * C_), dim3(256), 0, stream>>>(x, attn, out);
}